// Round 1
// baseline (3420.079 us; speedup 1.0000x reference)
//
#include <hip/hip_runtime.h>

typedef _Float16 f16;
typedef _Float16 f16x4 __attribute__((ext_vector_type(4)));
typedef _Float16 f16x8 __attribute__((ext_vector_type(8)));
typedef float f32x4 __attribute__((ext_vector_type(4)));

#define N_ 256
#define T_ 64
#define D_ 1024
#define H_ 1024
#define K3 3072
#define G4 4096

// ---------------- transpose Wx/Wh/Wattn (fp32, [k][j]) -> W3T (fp16, [j][k]) -----
__global__ void k_transpose(const float* __restrict__ Wx, const float* __restrict__ Wh,
                            const float* __restrict__ Wattn, f16* __restrict__ W3T) {
    __shared__ float tile[32][33];
    int j0 = blockIdx.x * 32;   // 128 blocks over j (4096)
    int k0 = blockIdx.y * 32;   // 96 blocks over k (3072)
    int tx = threadIdx.x;       // 32
    int ty = threadIdx.y;       // 8
    for (int i = 0; i < 4; i++) {
        int k = k0 + ty + i * 8;
        const float* W = (k < 1024) ? Wx : ((k < 2048) ? Wh : Wattn);
        int kr = k & 1023;
        tile[ty + i * 8][tx] = W[(size_t)kr * 4096 + j0 + tx];
    }
    __syncthreads();
    for (int i = 0; i < 4; i++) {
        int j = j0 + ty + i * 8;
        W3T[(size_t)j * K3 + k0 + tx] = (f16)tile[tx][ty + i * 8];
    }
}

// ---------------- init: h0 = c0 = mean(A over 16); scores_0 = h0 . A ------------
__global__ void k_init(const float* __restrict__ A, f16* __restrict__ Zh,
                       float* __restrict__ c, float* __restrict__ scores) {
    int n = blockIdx.x;
    int tid = threadIdx.x;
    __shared__ float sred[256][16];
    float s[16];
#pragma unroll
    for (int l = 0; l < 16; l++) s[l] = 0.f;
    for (int i = 0; i < 4; i++) {
        int h = tid + i * 256;
        const float* Ap = A + (size_t)n * 16384 + h * 16;
        float a[16];
        float sum = 0.f;
#pragma unroll
        for (int l = 0; l < 16; l++) { a[l] = Ap[l]; sum += a[l]; }
        float h0 = sum * (1.f / 16.f);
        c[n * 1024 + h] = h0;
        Zh[n * 1024 + h] = (f16)h0;
#pragma unroll
        for (int l = 0; l < 16; l++) s[l] += h0 * a[l];
    }
#pragma unroll
    for (int l = 0; l < 16; l++) sred[tid][l] = s[l];
    __syncthreads();
    for (int st = 128; st > 0; st >>= 1) {
        if (tid < st) {
#pragma unroll
            for (int l = 0; l < 16; l++) sred[tid][l] += sred[tid + st][l];
        }
        __syncthreads();
    }
    if (tid < 16) scores[n * 16 + tid] = sred[0][tid];
}

// ---------------- attention: softmax(scores*scale) -> attn; re-zero scores -------
__global__ void k_attn(const float* __restrict__ A, float* __restrict__ scores,
                       f16* __restrict__ Za) {
    int n = blockIdx.x;
    int tid = threadIdx.x;
    float w[16];
    float mx = -1e30f;
#pragma unroll
    for (int l = 0; l < 16; l++) { w[l] = scores[n * 16 + l] * 0.03125f; mx = fmaxf(mx, w[l]); }
    float sum = 0.f;
#pragma unroll
    for (int l = 0; l < 16; l++) { w[l] = __expf(w[l] - mx); sum += w[l]; }
    float inv = 1.f / sum;
#pragma unroll
    for (int l = 0; l < 16; l++) w[l] *= inv;
    __syncthreads();               // everyone has read scores
    if (tid < 16) scores[n * 16 + tid] = 0.f;   // ready for next step's atomics
    for (int i = 0; i < 4; i++) {
        int h = tid + i * 256;
        const float* Ap = A + (size_t)n * 16384 + h * 16;
        float acc = 0.f;
#pragma unroll
        for (int l = 0; l < 16; l++) acc += Ap[l] * w[l];
        Za[n * 1024 + h] = (f16)acc;
    }
}

// ---------------- one LSTM step: a = [xt|h|attn] @ W3 + b; gates; h,c update -----
// grid 256 = (4 n-tiles of 64) x (64 h-tiles of 16); 256 thr = 4 waves,
// wave w computes gate segment w (cols w*1024 + [hc,hc+16)).
__global__ __launch_bounds__(256, 2) void k_step(
    const float* __restrict__ x, const f16* __restrict__ W3T,
    const f16* __restrict__ Zin, f16* __restrict__ Zout,
    const f16* __restrict__ Za, const float* __restrict__ A,
    const float* __restrict__ b, float* __restrict__ c,
    float* __restrict__ scores, float* __restrict__ out, int t) {
    __shared__ f16 As[64 * 136];      // A-tile [n][k], pad 8
    __shared__ f16 Bs[4][16 * 136];   // per-wave B panel [j][k]
    __shared__ float Gs[4][64 * 17];  // gate preacts
    __shared__ float Hs[64 * 17];     // new h

    int tid = threadIdx.x;
    int wave = tid >> 6;
    int lane = tid & 63;
    int n0 = (blockIdx.x & 3) * 64;
    int ht = blockIdx.x >> 2;
    int hc = ht * 16;
    int jc = wave * 1024 + hc;        // B rows in W3T for this wave

    f32x4 acc[4];
#pragma unroll
    for (int m = 0; m < 4; m++) acc[m] = (f32x4){0.f, 0.f, 0.f, 0.f};

    int m16 = lane & 15;
    int quad = lane >> 4;

    for (int kc = 0; kc < K3; kc += 128) {
        int seg = kc >> 10;
        int ko = kc & 1023;
        // ---- stage A-tile (64 n x 128 k) ----
        if (seg == 0) {
            // from fp32 x, convert
            for (int i = 0; i < 8; i++) {
                int idx = i * 256 + tid;
                int r = idx >> 5;          // 0..63
                int cc = idx & 31;         // float4 chunk
                const float* src = x + ((size_t)(n0 + r) * T_ + t) * 1024 + ko + cc * 4;
                float4 v = *(const float4*)src;
                f16x4 h4 = {(f16)v.x, (f16)v.y, (f16)v.z, (f16)v.w};
                *(f16x4*)(&As[r * 136 + cc * 4]) = h4;
            }
        } else {
            const f16* base = (seg == 1) ? Zin : Za;
            int koo = (seg == 1) ? (kc - 1024) : (kc - 2048);
            for (int i = 0; i < 4; i++) {
                int idx = i * 256 + tid;
                int r = idx >> 4;          // 0..63
                int cc = idx & 15;         // 8-f16 chunk
                const f16* src = base + (size_t)(n0 + r) * 1024 + koo + cc * 8;
                *(uint4*)(&As[r * 136 + cc * 8]) = *(const uint4*)src;
            }
        }
        // ---- stage B panel (16 j x 128 k) per wave ----
        for (int i = 0; i < 4; i++) {
            int idx = i * 64 + lane;
            int r = idx >> 4;
            int cc = idx & 15;
            const f16* src = W3T + (size_t)(jc + r) * K3 + kc + cc * 8;
            *(uint4*)(&Bs[wave][r * 136 + cc * 8]) = *(const uint4*)src;
        }
        __syncthreads();
        // ---- MFMA ----
#pragma unroll
        for (int ks = 0; ks < 4; ks++) {
            f16x8 bf = *(const f16x8*)(&Bs[wave][m16 * 136 + ks * 32 + quad * 8]);
#pragma unroll
            for (int mt = 0; mt < 4; mt++) {
                f16x8 af = *(const f16x8*)(&As[(mt * 16 + m16) * 136 + ks * 32 + quad * 8]);
                acc[mt] = __builtin_amdgcn_mfma_f32_16x16x32_f16(af, bf, acc[mt], 0, 0, 0);
            }
        }
        __syncthreads();
    }

    // ---- dump gate preacts to LDS ----
#pragma unroll
    for (int mt = 0; mt < 4; mt++) {
#pragma unroll
        for (int r = 0; r < 4; r++) {
            int nn = mt * 16 + quad * 4 + r;
            Gs[wave][nn * 17 + m16] = acc[mt][r];
        }
    }
    __syncthreads();

    // ---- gates + state update: 64n x 16h, 4 per thread ----
    for (int i = 0; i < 4; i++) {
        int idx = i * 256 + tid;
        int nn = idx >> 4;
        int hh = idx & 15;
        int gn = n0 + nn;
        int gh = hc + hh;
        float ai = Gs[0][nn * 17 + hh] + b[gh];
        float af = Gs[1][nn * 17 + hh] + b[1024 + gh];
        float ao = Gs[2][nn * 17 + hh] + b[2048 + gh];
        float ag = Gs[3][nn * 17 + hh] + b[3072 + gh];
        float ig = 1.f / (1.f + __expf(-ai));
        float fg = 1.f / (1.f + __expf(-af));
        float og = 1.f / (1.f + __expf(-ao));
        float gg = tanhf(ag);
        float cn = fg * c[gn * 1024 + gh] + ig * gg;
        c[gn * 1024 + gh] = cn;
        float hn = og * tanhf(cn);
        out[((size_t)gn * T_ + t) * 1024 + gh] = hn;
        Zout[gn * 1024 + gh] = (f16)hn;
        Hs[nn * 17 + hh] = hn;
    }
    __syncthreads();

    // ---- partial scores for next step: 64n x 16l, 4 per thread ----
    for (int i = 0; i < 4; i++) {
        int idx = i * 256 + tid;
        int nn = idx >> 4;
        int l = idx & 15;
        int gn = n0 + nn;
        float s = 0.f;
#pragma unroll
        for (int hh = 0; hh < 16; hh++)
            s += Hs[nn * 17 + hh] * A[(size_t)gn * 16384 + (hc + hh) * 16 + l];
        atomicAdd(&scores[gn * 16 + l], s);
    }
}

extern "C" void kernel_launch(void* const* d_in, const int* in_sizes, int n_in,
                              void* d_out, int out_size, void* d_ws, size_t ws_size,
                              hipStream_t stream) {
    const float* x     = (const float*)d_in[0];
    const float* A     = (const float*)d_in[1];
    const float* Wx    = (const float*)d_in[2];
    const float* Wh    = (const float*)d_in[3];
    const float* Wattn = (const float*)d_in[4];
    const float* b     = (const float*)d_in[5];
    float* out = (float*)d_out;

    char* ws = (char*)d_ws;
    size_t off = 0;
    f16* W3T = (f16*)(ws + off); off += (size_t)G4 * K3 * 2;       // 25,165,824
    f16* Zh0 = (f16*)(ws + off); off += (size_t)N_ * H_ * 2;       // 524,288
    f16* Zh1 = (f16*)(ws + off); off += (size_t)N_ * H_ * 2;       // 524,288
    f16* Za  = (f16*)(ws + off); off += (size_t)N_ * H_ * 2;       // 524,288
    float* c = (float*)(ws + off); off += (size_t)N_ * H_ * 4;     // 1,048,576
    float* scores = (float*)(ws + off); off += (size_t)N_ * 16 * 4;

    k_transpose<<<dim3(128, 96), dim3(32, 8), 0, stream>>>(Wx, Wh, Wattn, W3T);
    k_init<<<256, 256, 0, stream>>>(A, Zh0, c, scores);
    for (int t = 0; t < T_; t++) {
        f16* Zin  = (t & 1) ? Zh1 : Zh0;
        f16* Zout = (t & 1) ? Zh0 : Zh1;
        k_attn<<<256, 256, 0, stream>>>(A, scores, Za);
        k_step<<<256, 256, 0, stream>>>(x, W3T, Zin, Zout, Za, A, b, c, scores, out, t);
    }
}

// Round 2
// 2713.698 us; speedup vs baseline: 1.2603x; 1.2603x over previous
//
#include <hip/hip_runtime.h>

typedef _Float16 f16;
typedef _Float16 f16x4 __attribute__((ext_vector_type(4)));
typedef _Float16 f16x8 __attribute__((ext_vector_type(8)));
typedef float f32x4 __attribute__((ext_vector_type(4)));

#define N_ 256
#define T_ 64
#define D_ 1024
#define H_ 1024
#define K3 3072
#define G4 4096

// ---------------- transpose Wx/Wh/Wattn (fp32, [k][j]) -> W3T (fp16, [j][k]) -----
__global__ void k_transpose(const float* __restrict__ Wx, const float* __restrict__ Wh,
                            const float* __restrict__ Wattn, f16* __restrict__ W3T) {
    __shared__ float tile[32][33];
    int j0 = blockIdx.x * 32;   // 128 blocks over j (4096)
    int k0 = blockIdx.y * 32;   // 96 blocks over k (3072)
    int tx = threadIdx.x;       // 32
    int ty = threadIdx.y;       // 8
    for (int i = 0; i < 4; i++) {
        int k = k0 + ty + i * 8;
        const float* W = (k < 1024) ? Wx : ((k < 2048) ? Wh : Wattn);
        int kr = k & 1023;
        tile[ty + i * 8][tx] = W[(size_t)kr * 4096 + j0 + tx];
    }
    __syncthreads();
    for (int i = 0; i < 4; i++) {
        int j = j0 + ty + i * 8;
        W3T[(size_t)j * K3 + k0 + tx] = (f16)tile[tx][ty + i * 8];
    }
}

// ---------------- cast A (fp32) -> A16 (f16), 4 elements/thread ------------------
__global__ void k_castA(const float* __restrict__ A, f16* __restrict__ A16) {
    int i = blockIdx.x * 256 + threadIdx.x;
    float4 v = ((const float4*)A)[i];
    f16x4 h4 = {(f16)v.x, (f16)v.y, (f16)v.z, (f16)v.w};
    ((f16x4*)A16)[i] = h4;
}

// ---------------- init: h0 = c0 = mean(A over 16) -------------------------------
__global__ void k_init(const float* __restrict__ A, f16* __restrict__ Zh,
                       float* __restrict__ c) {
    int n = blockIdx.x;
    int tid = threadIdx.x;
    for (int i = 0; i < 4; i++) {
        int h = tid + i * 256;
        const float* Ap = A + (size_t)n * 16384 + h * 16;
        float sum = 0.f;
#pragma unroll
        for (int l = 0; l < 16; l++) sum += Ap[l];
        float h0 = sum * (1.f / 16.f);
        c[n * 1024 + h] = h0;
        Zh[n * 1024 + h] = (f16)h0;
    }
}

// ---------------- attention: scores = h.A; softmax; attn = A.w -------------------
// grid 256 (one block per n), 256 threads; thread owns 4 contiguous h.
__global__ void k_attn(const f16* __restrict__ A16, const f16* __restrict__ Zin,
                       f16* __restrict__ Za) {
    int n = blockIdx.x;
    int tid = threadIdx.x;
    __shared__ float sred[256][16];
    float s[16];
#pragma unroll
    for (int l = 0; l < 16; l++) s[l] = 0.f;
    for (int i = 0; i < 4; i++) {
        int h = tid * 4 + i;
        float hv = (float)Zin[n * 1024 + h];
        const f16* Ap = A16 + (size_t)n * 16384 + h * 16;
        f16x8 a0 = *(const f16x8*)(Ap);
        f16x8 a1 = *(const f16x8*)(Ap + 8);
#pragma unroll
        for (int l = 0; l < 8; l++) { s[l] += hv * (float)a0[l]; s[l + 8] += hv * (float)a1[l]; }
    }
#pragma unroll
    for (int l = 0; l < 16; l++) sred[tid][l] = s[l];
    __syncthreads();
    for (int st = 128; st > 0; st >>= 1) {
        if (tid < st) {
#pragma unroll
            for (int l = 0; l < 16; l++) sred[tid][l] += sred[tid + st][l];
        }
        __syncthreads();
    }
    // softmax (computed redundantly by all threads; sred[0][*] broadcasts)
    float w[16];
    float mx = -1e30f;
#pragma unroll
    for (int l = 0; l < 16; l++) { w[l] = sred[0][l] * 0.03125f; mx = fmaxf(mx, w[l]); }
    float sum = 0.f;
#pragma unroll
    for (int l = 0; l < 16; l++) { w[l] = __expf(w[l] - mx); sum += w[l]; }
    float inv = 1.f / sum;
#pragma unroll
    for (int l = 0; l < 16; l++) w[l] *= inv;
    for (int i = 0; i < 4; i++) {
        int h = tid * 4 + i;
        const f16* Ap = A16 + (size_t)n * 16384 + h * 16;
        f16x8 a0 = *(const f16x8*)(Ap);
        f16x8 a1 = *(const f16x8*)(Ap + 8);
        float acc = 0.f;
#pragma unroll
        for (int l = 0; l < 8; l++) acc += (float)a0[l] * w[l] + (float)a1[l] * w[l + 8];
        Za[n * 1024 + h] = (f16)acc;
    }
}

// ---------------- one LSTM step: a = [xt|h|attn] @ W3 + b; gates; h,c update -----
// grid 512 = 8 n-tiles(32) x 64 h-tiles(16); decode ht = bid&63 so that
// XCD = bid%8 = ht%8 -> each XCD's weight slice is 3 MB, L2-resident across steps.
// 256 thr = 4 waves; wave w computes gate segment w (cols w*1024+[hc,hc+16)).
__global__ __launch_bounds__(256, 2) void k_step(
    const float* __restrict__ x, const f16* __restrict__ W3T,
    const f16* __restrict__ Zin, f16* __restrict__ Zout,
    const f16* __restrict__ Za, const float* __restrict__ b,
    float* __restrict__ c, float* __restrict__ out, int t) {
    __shared__ f16 As[32 * 136];      // A-tile [n][k], pad 8
    __shared__ f16 Bs[4][16 * 136];   // per-wave B panel [j][k]
    __shared__ float Gs[4][32 * 17];  // gate preacts

    int tid = threadIdx.x;
    int wave = tid >> 6;
    int lane = tid & 63;
    int bid = blockIdx.x;
    int ht = bid & 63;
    int n0 = (bid >> 6) * 32;
    int hc = ht * 16;
    int jc = wave * 1024 + hc;        // B rows in W3T for this wave

    f32x4 acc[2];
#pragma unroll
    for (int m = 0; m < 2; m++) acc[m] = (f32x4){0.f, 0.f, 0.f, 0.f};

    int m16 = lane & 15;
    int quad = lane >> 4;

    for (int kc = 0; kc < K3; kc += 128) {
        int seg = kc >> 10;
        int ko = kc & 1023;
        // ---- stage A-tile (32 n x 128 k) ----
        if (seg == 0) {
            for (int i = 0; i < 4; i++) {
                int idx = i * 256 + tid;
                int r = idx >> 5;          // 0..31
                int cc = idx & 31;         // float4 chunk
                const float* src = x + ((size_t)(n0 + r) * T_ + t) * 1024 + ko + cc * 4;
                float4 v = *(const float4*)src;
                f16x4 h4 = {(f16)v.x, (f16)v.y, (f16)v.z, (f16)v.w};
                *(f16x4*)(&As[r * 136 + cc * 4]) = h4;
            }
        } else {
            const f16* base = (seg == 1) ? Zin : Za;
            int koo = kc - seg * 1024;
            for (int i = 0; i < 2; i++) {
                int idx = i * 256 + tid;
                int r = idx >> 4;          // 0..31
                int cc = idx & 15;         // 8-f16 chunk
                const f16* src = base + (size_t)(n0 + r) * 1024 + koo + cc * 8;
                *(uint4*)(&As[r * 136 + cc * 8]) = *(const uint4*)src;
            }
        }
        // ---- stage B panel (16 j x 128 k) per wave ----
        for (int i = 0; i < 4; i++) {
            int idx = i * 64 + lane;
            int r = idx >> 4;
            int cc = idx & 15;
            const f16* src = W3T + (size_t)(jc + r) * K3 + kc + cc * 8;
            *(uint4*)(&Bs[wave][r * 136 + cc * 8]) = *(const uint4*)src;
        }
        __syncthreads();
        // ---- MFMA ----
#pragma unroll
        for (int ks = 0; ks < 4; ks++) {
            f16x8 bf = *(const f16x8*)(&Bs[wave][m16 * 136 + ks * 32 + quad * 8]);
#pragma unroll
            for (int mt = 0; mt < 2; mt++) {
                f16x8 af = *(const f16x8*)(&As[(mt * 16 + m16) * 136 + ks * 32 + quad * 8]);
                acc[mt] = __builtin_amdgcn_mfma_f32_16x16x32_f16(af, bf, acc[mt], 0, 0, 0);
            }
        }
        __syncthreads();
    }

    // ---- dump gate preacts to LDS ----
#pragma unroll
    for (int mt = 0; mt < 2; mt++) {
#pragma unroll
        for (int r = 0; r < 4; r++) {
            int nn = mt * 16 + quad * 4 + r;
            Gs[wave][nn * 17 + m16] = acc[mt][r];
        }
    }
    __syncthreads();

    // ---- gates + state update: 32n x 16h, 2 per thread ----
    for (int i = 0; i < 2; i++) {
        int idx = i * 256 + tid;
        int nn = idx >> 4;
        int hh = idx & 15;
        int gn = n0 + nn;
        int gh = hc + hh;
        float ai = Gs[0][nn * 17 + hh] + b[gh];
        float af = Gs[1][nn * 17 + hh] + b[1024 + gh];
        float ao = Gs[2][nn * 17 + hh] + b[2048 + gh];
        float ag = Gs[3][nn * 17 + hh] + b[3072 + gh];
        float ig = 1.f / (1.f + __expf(-ai));
        float fg = 1.f / (1.f + __expf(-af));
        float og = 1.f / (1.f + __expf(-ao));
        float gg = tanhf(ag);
        float cn = fg * c[gn * 1024 + gh] + ig * gg;
        c[gn * 1024 + gh] = cn;
        float hn = og * tanhf(cn);
        out[((size_t)gn * T_ + t) * 1024 + gh] = hn;
        Zout[gn * 1024 + gh] = (f16)hn;
    }
}

extern "C" void kernel_launch(void* const* d_in, const int* in_sizes, int n_in,
                              void* d_out, int out_size, void* d_ws, size_t ws_size,
                              hipStream_t stream) {
    const float* x     = (const float*)d_in[0];
    const float* A     = (const float*)d_in[1];
    const float* Wx    = (const float*)d_in[2];
    const float* Wh    = (const float*)d_in[3];
    const float* Wattn = (const float*)d_in[4];
    const float* b     = (const float*)d_in[5];
    float* out = (float*)d_out;

    char* ws = (char*)d_ws;
    size_t off = 0;
    f16* W3T = (f16*)(ws + off); off += (size_t)G4 * K3 * 2;       // 25,165,824
    f16* A16 = (f16*)(ws + off); off += (size_t)N_ * H_ * 16 * 2;  // 8,388,608
    f16* Zh0 = (f16*)(ws + off); off += (size_t)N_ * H_ * 2;       // 524,288
    f16* Zh1 = (f16*)(ws + off); off += (size_t)N_ * H_ * 2;       // 524,288
    f16* Za  = (f16*)(ws + off); off += (size_t)N_ * H_ * 2;       // 524,288
    float* c = (float*)(ws + off); off += (size_t)N_ * H_ * 4;     // 1,048,576

    k_transpose<<<dim3(128, 96), dim3(32, 8), 0, stream>>>(Wx, Wh, Wattn, W3T);
    k_castA<<<4096, 256, 0, stream>>>(A, A16);
    k_init<<<256, 256, 0, stream>>>(A, Zh0, c);
    for (int t = 0; t < T_; t++) {
        f16* Zin  = (t & 1) ? Zh1 : Zh0;
        f16* Zout = (t & 1) ? Zh0 : Zh1;
        k_attn<<<256, 256, 0, stream>>>(A16, Zin, Za);
        k_step<<<512, 256, 0, stream>>>(x, W3T, Zin, Zout, Za, b, c, out, t);
    }
}

// Round 3
// 2240.101 us; speedup vs baseline: 1.5268x; 1.2114x over previous
//
#include <hip/hip_runtime.h>

typedef _Float16 f16;
typedef _Float16 f16x4 __attribute__((ext_vector_type(4)));
typedef _Float16 f16x8 __attribute__((ext_vector_type(8)));
typedef float f32x4 __attribute__((ext_vector_type(4)));

#define N_ 256
#define T_ 64
#define D_ 1024
#define H_ 1024
#define K3 3072
#define G4 4096

// ---------------- transpose Wx/Wh/Wattn (fp32, [k][j]) -> W3T (fp16, [j][k]) -----
__global__ void k_transpose(const float* __restrict__ Wx, const float* __restrict__ Wh,
                            const float* __restrict__ Wattn, f16* __restrict__ W3T) {
    __shared__ float tile[32][33];
    int j0 = blockIdx.x * 32;   // 128 blocks over j (4096)
    int k0 = blockIdx.y * 32;   // 96 blocks over k (3072)
    int tx = threadIdx.x;       // 32
    int ty = threadIdx.y;       // 8
    for (int i = 0; i < 4; i++) {
        int k = k0 + ty + i * 8;
        const float* W = (k < 1024) ? Wx : ((k < 2048) ? Wh : Wattn);
        int kr = k & 1023;
        tile[ty + i * 8][tx] = W[(size_t)kr * 4096 + j0 + tx];
    }
    __syncthreads();
    for (int i = 0; i < 4; i++) {
        int j = j0 + ty + i * 8;
        W3T[(size_t)j * K3 + k0 + tx] = (f16)tile[tx][ty + i * 8];
    }
}

// ---------------- cast A (fp32) -> A16 (f16) -------------------------------------
__global__ void k_castA(const float* __restrict__ A, f16* __restrict__ A16) {
    int i = blockIdx.x * 256 + threadIdx.x;
    float4 v = ((const float4*)A)[i];
    f16x4 h4 = {(f16)v.x, (f16)v.y, (f16)v.z, (f16)v.w};
    ((f16x4*)A16)[i] = h4;
}

// ---------------- cast x (fp32) -> x16 (f16), 8 elems/thread ---------------------
__global__ void k_castX(const float* __restrict__ x, f16* __restrict__ x16) {
    size_t i = (size_t)blockIdx.x * 2048 + (size_t)threadIdx.x * 8;
    float4 v0 = *(const float4*)(x + i);
    float4 v1 = *(const float4*)(x + i + 4);
    f16x8 h;
    h[0] = (f16)v0.x; h[1] = (f16)v0.y; h[2] = (f16)v0.z; h[3] = (f16)v0.w;
    h[4] = (f16)v1.x; h[5] = (f16)v1.y; h[6] = (f16)v1.z; h[7] = (f16)v1.w;
    *(f16x8*)(x16 + i) = h;
}

// ---------------- init: h0 = c0 = mean(A); spart[0][n][:] = h0.A; zero rest ------
__global__ void k_init(const float* __restrict__ A, f16* __restrict__ Zh,
                       float* __restrict__ c, float* __restrict__ spart) {
    int n = blockIdx.x;
    int tid = threadIdx.x;
    __shared__ float sred[256][16];
    float s[16];
#pragma unroll
    for (int l = 0; l < 16; l++) s[l] = 0.f;
    for (int i = 0; i < 4; i++) {
        int h = tid + i * 256;
        const float* Ap = A + (size_t)n * 16384 + h * 16;
        float a[16];
        float sum = 0.f;
#pragma unroll
        for (int l = 0; l < 16; l++) { a[l] = Ap[l]; sum += a[l]; }
        float h0 = sum * (1.f / 16.f);
        c[n * 1024 + h] = h0;
        Zh[n * 1024 + h] = (f16)h0;
#pragma unroll
        for (int l = 0; l < 16; l++) s[l] += h0 * a[l];
    }
#pragma unroll
    for (int l = 0; l < 16; l++) sred[tid][l] = s[l];
    __syncthreads();
    for (int st = 128; st > 0; st >>= 1) {
        if (tid < st) {
#pragma unroll
            for (int l = 0; l < 16; l++) sred[tid][l] += sred[tid + st][l];
        }
        __syncthreads();
    }
    if (tid < 16) spart[(size_t)n * 16 + tid] = sred[0][tid];   // slab ht=0
    // zero slabs ht=1..63 for this n: 1008 entries
    for (int i = 0; i < 4; i++) {
        int idx = tid * 4 + i;
        if (idx < 1008) {
            int ht = 1 + (idx >> 4);
            int l = idx & 15;
            spart[((size_t)ht * 256 + n) * 16 + l] = 0.f;
        }
    }
}

// ---------------- attention: reduce spart -> softmax -> attn = A.w ---------------
__global__ void k_attn(const float* __restrict__ spart, const f16* __restrict__ A16,
                       f16* __restrict__ Za) {
    int n = blockIdx.x;
    int tid = threadIdx.x;
    __shared__ float sred[16][17];
    __shared__ float sfin[16];
    int g = tid >> 4;      // 0..15
    int l = tid & 15;
    float p = 0.f;
#pragma unroll
    for (int i = 0; i < 4; i++) {
        int ht = g + i * 16;
        p += spart[((size_t)ht * 256 + n) * 16 + l];
    }
    sred[g][l] = p;
    __syncthreads();
    if (tid < 16) {
        float s = 0.f;
#pragma unroll
        for (int gg = 0; gg < 16; gg++) s += sred[gg][tid];
        sfin[tid] = s;
    }
    __syncthreads();
    float w[16];
    float mx = -1e30f;
#pragma unroll
    for (int ll = 0; ll < 16; ll++) { w[ll] = sfin[ll] * 0.03125f; mx = fmaxf(mx, w[ll]); }
    float sum = 0.f;
#pragma unroll
    for (int ll = 0; ll < 16; ll++) { w[ll] = __expf(w[ll] - mx); sum += w[ll]; }
    float inv = 1.f / sum;
#pragma unroll
    for (int ll = 0; ll < 16; ll++) w[ll] *= inv;
    for (int i = 0; i < 4; i++) {
        int h = tid * 4 + i;
        const f16* Ap = A16 + (size_t)n * 16384 + h * 16;
        f16x8 a0 = *(const f16x8*)(Ap);
        f16x8 a1 = *(const f16x8*)(Ap + 8);
        float acc = 0.f;
#pragma unroll
        for (int ll = 0; ll < 8; ll++) acc += (float)a0[ll] * w[ll] + (float)a1[ll] * w[ll + 8];
        Za[n * 1024 + h] = (f16)acc;
    }
}

// ---------------- one LSTM step, barrier-free register-streaming GEMM ------------
// grid 256 = 4 nt(64) x 64 ht(16 h-cols); XCD = bid%8 = ht%8 -> 3 MB weight slice
// stays L2-resident across all 64 steps. Block = 512 thr = 8 waves, wave w owns
// K-slice [w*384,(w+1)*384). Each wave computes ALL 4 gates for its A-fragments
// (A-redundancy 1x), operands loaded straight from L2 in MFMA fragment layout —
// no LDS, no barriers in the K-loop.
__global__ __launch_bounds__(512, 2) void k_step(
    const f16* __restrict__ x16, const f16* __restrict__ W3T,
    const f16* __restrict__ Zin, f16* __restrict__ Zout,
    const f16* __restrict__ Za, const f16* __restrict__ A16,
    const float* __restrict__ b, float* __restrict__ c,
    float* __restrict__ spart, float* __restrict__ out, int t) {
    __shared__ float Gs[4][4][64 * 17];   // [slab][gate][nn*17+hh]  69.6 KB
    __shared__ float Hs[64 * 17];

    int tid = threadIdx.x;
    int wave = tid >> 6;          // 0..7 = K-slice
    int lane = tid & 63;
    int m16 = lane & 15;
    int quad = lane >> 4;
    int bid = blockIdx.x;
    int ht = bid & 63;
    int n0 = (bid >> 6) << 6;     // 0,64,128,192
    int hc = ht * 16;

    f32x4 acc[4][4];              // [gate][mt]
#pragma unroll
    for (int g = 0; g < 4; g++)
#pragma unroll
        for (int m = 0; m < 4; m++) acc[g][m] = (f32x4){0.f, 0.f, 0.f, 0.f};

    const f16* brow[4];
#pragma unroll
    for (int g = 0; g < 4; g++)
        brow[g] = W3T + (size_t)(g * 1024 + hc + m16) * K3 + quad * 8;

    size_t offx[4], offz[4];
#pragma unroll
    for (int mt = 0; mt < 4; mt++) {
        int n = n0 + mt * 16 + m16;
        offx[mt] = (size_t)n * (T_ * 1024);
        offz[mt] = (size_t)n * 1024;
    }
    const f16* xbase = x16 + (size_t)t * 1024 + quad * 8;
    const f16* zbase0 = Zin + quad * 8;
    const f16* zbase1 = Za + quad * 8;

    int kbase = wave * 384;
#pragma unroll 2
    for (int s = 0; s < 12; s++) {
        int k = kbase + s * 32;
        int seg = k >> 10;
        int kk = k & 1023;
        const f16* base;
        const size_t* off;
        if (seg == 0)      { base = xbase;  off = offx; }
        else if (seg == 1) { base = zbase0; off = offz; }
        else               { base = zbase1; off = offz; }
        f16x8 a[4], bb[4];
#pragma unroll
        for (int mt = 0; mt < 4; mt++) a[mt] = *(const f16x8*)(base + off[mt] + kk);
#pragma unroll
        for (int g = 0; g < 4; g++) bb[g] = *(const f16x8*)(brow[g] + k);
#pragma unroll
        for (int g = 0; g < 4; g++)
#pragma unroll
            for (int mt = 0; mt < 4; mt++)
                acc[g][mt] = __builtin_amdgcn_mfma_f32_16x16x32_f16(a[mt], bb[g], acc[g][mt], 0, 0, 0);
    }

    // ---- reduce 8 K-slice waves via 4 slabs: write then owner-add ----
    if (wave < 4) {
#pragma unroll
        for (int g = 0; g < 4; g++)
#pragma unroll
            for (int mt = 0; mt < 4; mt++)
#pragma unroll
                for (int r = 0; r < 4; r++)
                    Gs[wave][g][(mt * 16 + quad * 4 + r) * 17 + m16] = acc[g][mt][r];
    }
    __syncthreads();
    if (wave >= 4) {
        int sl = wave - 4;
#pragma unroll
        for (int g = 0; g < 4; g++)
#pragma unroll
            for (int mt = 0; mt < 4; mt++)
#pragma unroll
                for (int r = 0; r < 4; r++)
                    Gs[sl][g][(mt * 16 + quad * 4 + r) * 17 + m16] += acc[g][mt][r];
    }
    __syncthreads();

    // ---- gates + state update: 64n x 16h = 1024, 2 per thread ----
    for (int i = 0; i < 2; i++) {
        int idx = i * 512 + tid;
        int nn = idx >> 4;
        int hh = idx & 15;
        int gi = nn * 17 + hh;
        int gn = n0 + nn;
        int gh = hc + hh;
        float ai = Gs[0][0][gi] + Gs[1][0][gi] + Gs[2][0][gi] + Gs[3][0][gi] + b[gh];
        float af = Gs[0][1][gi] + Gs[1][1][gi] + Gs[2][1][gi] + Gs[3][1][gi] + b[1024 + gh];
        float ao = Gs[0][2][gi] + Gs[1][2][gi] + Gs[2][2][gi] + Gs[3][2][gi] + b[2048 + gh];
        float ag = Gs[0][3][gi] + Gs[1][3][gi] + Gs[2][3][gi] + Gs[3][3][gi] + b[3072 + gh];
        float ig = 1.f / (1.f + __expf(-ai));
        float fg = 1.f / (1.f + __expf(-af));
        float og = 1.f / (1.f + __expf(-ao));
        float gg = tanhf(ag);
        float cn = fg * c[gn * 1024 + gh] + ig * gg;
        c[gn * 1024 + gh] = cn;
        float hn = og * tanhf(cn);
        out[((size_t)gn * T_ + t) * 1024 + gh] = hn;
        Zout[gn * 1024 + gh] = (f16)hn;
        Hs[gi] = hn;
    }
    __syncthreads();

    // ---- partial scores vs local A16 slice (32 KB): 64n x 16l, 2 per thread ----
    for (int i = 0; i < 2; i++) {
        int idx = i * 512 + tid;
        int nn = idx >> 4;
        int l = idx & 15;
        int gn = n0 + nn;
        const f16* Ap = A16 + (size_t)gn * 16384 + hc * 16 + l;
        float s = 0.f;
#pragma unroll
        for (int hh = 0; hh < 16; hh++)
            s += Hs[nn * 17 + hh] * (float)Ap[hh * 16];
        spart[((size_t)ht * 256 + gn) * 16 + l] = s;
    }
}

extern "C" void kernel_launch(void* const* d_in, const int* in_sizes, int n_in,
                              void* d_out, int out_size, void* d_ws, size_t ws_size,
                              hipStream_t stream) {
    const float* x     = (const float*)d_in[0];
    const float* A     = (const float*)d_in[1];
    const float* Wx    = (const float*)d_in[2];
    const float* Wh    = (const float*)d_in[3];
    const float* Wattn = (const float*)d_in[4];
    const float* b     = (const float*)d_in[5];
    float* out = (float*)d_out;

    char* ws = (char*)d_ws;
    size_t off = 0;
    f16* W3T = (f16*)(ws + off); off += (size_t)G4 * K3 * 2;        // 25.2 MB
    f16* x16 = (f16*)(ws + off); off += (size_t)N_ * T_ * D_ * 2;   // 33.6 MB
    f16* A16 = (f16*)(ws + off); off += (size_t)N_ * H_ * 16 * 2;   // 8.4 MB
    f16* Zh0 = (f16*)(ws + off); off += (size_t)N_ * H_ * 2;
    f16* Zh1 = (f16*)(ws + off); off += (size_t)N_ * H_ * 2;
    f16* Za  = (f16*)(ws + off); off += (size_t)N_ * H_ * 2;
    float* c = (float*)(ws + off); off += (size_t)N_ * H_ * 4;      // 1 MB
    float* spart = (float*)(ws + off); off += (size_t)64 * N_ * 16 * 4; // 1 MB

    k_transpose<<<dim3(128, 96), dim3(32, 8), 0, stream>>>(Wx, Wh, Wattn, W3T);
    k_castA<<<4096, 256, 0, stream>>>(A, A16);
    k_castX<<<8192, 256, 0, stream>>>(x, x16);
    k_init<<<256, 256, 0, stream>>>(A, Zh0, c, spart);
    for (int t = 0; t < T_; t++) {
        f16* Zin  = (t & 1) ? Zh1 : Zh0;
        f16* Zout = (t & 1) ? Zh0 : Zh1;
        k_attn<<<256, 256, 0, stream>>>(spart, A16, Za);
        k_step<<<256, 512, 0, stream>>>(x16, W3T, Zin, Zout, Za, A16, b, c, spart, out, t);
    }
}